// Round 8
// baseline (240.533 us; speedup 1.0000x reference)
//
#include <hip/hip_runtime.h>

// ---------------------------------------------------------------------------
// 3-layer GCN: per layer  g = dinv * (x@W) [bf16, MFMA 16x16x32] ;
//              out[i] = relu( dinv[i]*(sum_{e:dst=i} g[src_e] + g[i]) + b )
// R7: agg = 2 nodes/wave with interleaved 2-stage pipelines (8 gathers in
// flight/wave); count_rank & fill process 4 edges/thread (int4 batching).
// ---------------------------------------------------------------------------

typedef __attribute__((ext_vector_type(8))) unsigned short ushort8;
typedef __attribute__((ext_vector_type(8))) short short8v;
typedef __attribute__((ext_vector_type(4))) float f32x4;

__device__ __forceinline__ unsigned short f2bf(float f) {
    unsigned u = __float_as_uint(f);
    unsigned r = (u + 0x7FFF + ((u >> 16) & 1)) >> 16;   // RNE
    return (unsigned short)r;
}
__device__ __forceinline__ float bf2f(unsigned short s) {
    return __uint_as_float(((unsigned)s) << 16);
}

__global__ __launch_bounds__(256) void zero_kernel(int4* __restrict__ p, int n4) {
    int i = blockIdx.x * 256 + threadIdx.x;
    if (i < n4) p[i] = make_int4(0, 0, 0, 0);
}

// 4 edges/thread: 4 independent atomic chains, coalesced int4 rank write
__global__ void count_rank_kernel(const int* __restrict__ ei, int* __restrict__ cnt,
                                  int* __restrict__ rank, int E) {
    int e = (blockIdx.x * blockDim.x + threadIdx.x) * 4;
    if (e + 4 <= E) {
        int4 d4 = *(const int4*)(ei + E + e);
        int4 r;
        r.x = atomicAdd(&cnt[d4.x], 1);
        r.y = atomicAdd(&cnt[d4.y], 1);
        r.z = atomicAdd(&cnt[d4.z], 1);
        r.w = atomicAdd(&cnt[d4.w], 1);
        *(int4*)(rank + e) = r;
    } else {
        for (; e < E; ++e) rank[e] = atomicAdd(&cnt[ei[E + e]], 1);
    }
}

__global__ __launch_bounds__(256) void block_sum_kernel(const int* __restrict__ cnt,
                                                        int* __restrict__ bsum, int n) {
    int i = blockIdx.x * 256 + threadIdx.x;
    int v = (i < n) ? cnt[i] : 0;
#pragma unroll
    for (int off = 32; off; off >>= 1) v += __shfl_down(v, off);
    __shared__ int ws[4];
    int lane = threadIdx.x & 63, w = threadIdx.x >> 6;
    if (lane == 0) ws[w] = v;
    __syncthreads();
    if (threadIdx.x == 0) bsum[blockIdx.x] = ws[0] + ws[1] + ws[2] + ws[3];
}

__global__ __launch_bounds__(256) void scan_partials_kernel(const int* __restrict__ bsum,
                                                            int* __restrict__ bpre,
                                                            int* __restrict__ rowptr,
                                                            int nb, int n) {
    __shared__ int sh[256];
    int t = threadIdx.x;
    int v = (t < nb) ? bsum[t] : 0;
    sh[t] = v;
    __syncthreads();
    for (int off = 1; off < 256; off <<= 1) {
        int u = (t >= off) ? sh[t - off] : 0;
        __syncthreads();
        sh[t] += u;
        __syncthreads();
    }
    if (t < nb) bpre[t] = sh[t] - v;
    if (t == 255) rowptr[n] = sh[255];
}

__global__ __launch_bounds__(256) void scan_write_kernel(const int* __restrict__ cnt,
                                                         const int* __restrict__ bpre,
                                                         int* __restrict__ rowptr,
                                                         float* __restrict__ dinv, int n) {
    __shared__ int sh[256];
    int t = threadIdx.x;
    int i = blockIdx.x * 256 + t;
    int c = (i < n) ? cnt[i] : 0;
    sh[t] = c;
    __syncthreads();
    for (int off = 1; off < 256; off <<= 1) {
        int u = (t >= off) ? sh[t - off] : 0;
        __syncthreads();
        sh[t] += u;
        __syncthreads();
    }
    if (i < n) {
        rowptr[i] = bpre[blockIdx.x] + sh[t] - c;
        dinv[i] = rsqrtf((float)(c + 1));   // +1 self loop
    }
}

// 4 edges/thread: 4 independent gather+store chains
__global__ void fill_kernel(const int* __restrict__ ei, const int* __restrict__ rowptr,
                            const int* __restrict__ rank, int* __restrict__ col, int E) {
    int e = (blockIdx.x * blockDim.x + threadIdx.x) * 4;
    if (e + 4 <= E) {
        int4 s4 = *(const int4*)(ei + e);
        int4 d4 = *(const int4*)(ei + E + e);
        int4 r4 = *(const int4*)(rank + e);
        int p0 = rowptr[d4.x] + r4.x;
        int p1 = rowptr[d4.y] + r4.y;
        int p2 = rowptr[d4.z] + r4.z;
        int p3 = rowptr[d4.w] + r4.w;
        col[p0] = s4.x;
        col[p1] = s4.y;
        col[p2] = s4.z;
        col[p3] = s4.w;
    } else {
        for (; e < E; ++e) col[rowptr[ei[E + e]] + rank[e]] = ei[e];
    }
}

// Pack 3 W[128][128] fp32 into per-lane bf16 B-fragments (one launch, 24 blocks)
__global__ __launch_bounds__(256) void wprep_kernel(const float* __restrict__ W0,
                                                    const float* __restrict__ W1,
                                                    const float* __restrict__ W2,
                                                    short* __restrict__ F0,
                                                    short* __restrict__ F1,
                                                    short* __restrict__ F2) {
    int which = blockIdx.x >> 3;
    const float* W = which == 0 ? W0 : (which == 1 ? W1 : W2);
    short* Wfrag   = which == 0 ? F0 : (which == 1 ? F1 : F2);
    int idx = (blockIdx.x & 7) * 256 + threadIdx.x;   // 0..2047
    int l = idx & 63;
    int cks = idx >> 6;
    int ks = cks & 3, c = cks >> 2;
    int col = c * 16 + (l & 15);
    int k0 = ks * 32 + (l >> 4) * 8;
    short8v o;
#pragma unroll
    for (int j = 0; j < 8; ++j) o[j] = (short)f2bf(W[(size_t)(k0 + j) * 128 + col]);
    ((short8v*)Wfrag)[idx] = o;
}

// G = dinv * (X @ W) via MFMA 16x16x32 bf16.
// C/D layout: col=lane&15, row=(lane>>4)*4+reg  [learn_hip m89].
template <bool IN_BF16>
__global__ __launch_bounds__(256) void gemm_mfma_kernel(const void* __restrict__ Xv,
                                                        const short* __restrict__ Wfrag,
                                                        const float* __restrict__ dinv,
                                                        unsigned short* __restrict__ G, int n) {
    int t = threadIdx.x;
    int wv = t >> 6, l = t & 63;
    int row0 = blockIdx.x * 64 + wv * 16;
    int r = l & 15, half = l >> 4;
    int arow = row0 + r;
    bool rok = arow < n;

    f32x4 acc[8];
#pragma unroll
    for (int c = 0; c < 8; ++c) acc[c] = (f32x4){0.f, 0.f, 0.f, 0.f};

    const short8v* WF = (const short8v*)Wfrag;

#pragma unroll
    for (int ks = 0; ks < 4; ++ks) {
        short8v a = (short8v){0, 0, 0, 0, 0, 0, 0, 0};
        if (rok) {
            if (IN_BF16) {
                const unsigned short* X = (const unsigned short*)Xv;
                a = *(const short8v*)(X + (size_t)arow * 128 + ks * 32 + half * 8);
            } else {
                const float* X = (const float*)Xv;
                const float4* xp = (const float4*)(X + (size_t)arow * 128 + ks * 32 + half * 8);
                float4 x0 = xp[0], x1 = xp[1];
                a[0] = (short)f2bf(x0.x); a[1] = (short)f2bf(x0.y);
                a[2] = (short)f2bf(x0.z); a[3] = (short)f2bf(x0.w);
                a[4] = (short)f2bf(x1.x); a[5] = (short)f2bf(x1.y);
                a[6] = (short)f2bf(x1.z); a[7] = (short)f2bf(x1.w);
            }
        }
#pragma unroll
        for (int c = 0; c < 8; ++c) {
            short8v b = WF[(c * 4 + ks) * 64 + l];
            acc[c] = __builtin_amdgcn_mfma_f32_16x16x32_bf16(a, b, acc[c], 0, 0, 0);
        }
    }

    float ds[4];
    int orow[4];
#pragma unroll
    for (int i = 0; i < 4; ++i) {
        orow[i] = row0 + half * 4 + i;
        ds[i] = (orow[i] < n) ? dinv[orow[i]] : 0.f;
    }
#pragma unroll
    for (int c = 0; c < 8; ++c) {
#pragma unroll
        for (int i = 0; i < 4; ++i) {
            if (orow[i] < n)
                G[(size_t)orow[i] * 128 + c * 16 + r] = f2bf(ds[i] * acc[c][i]);
        }
    }
}

// 2 nodes per wave, interleaved 2-stage pipelines: up to 8 gathers in flight.
// q=lane&15 -> feature octet (16B), p=lane>>4 -> edge slot 0..3.
template <bool OUT_BF16>
__global__ __launch_bounds__(256) void agg_kernel(const unsigned short* __restrict__ G,
                                                  const int* __restrict__ rowptr,
                                                  const int* __restrict__ col,
                                                  const float* __restrict__ dinv,
                                                  const float* __restrict__ b,
                                                  void* __restrict__ outv, int n) {
    int wid = (int)((blockIdx.x * blockDim.x + threadIdx.x) >> 6);
    int lane = threadIdx.x & 63;
    int q = lane & 15, p = lane >> 4;
    int gwA = wid * 2, gwB = gwA + 1;
    if (gwA >= n) return;
    bool okB = gwB < n;

    int begA = rowptr[gwA], endA = rowptr[gwA + 1];
    float diA = dinv[gwA];
    int begB = 0, endB = 0;
    float diB = 0.f;
    if (okB) { begB = rowptr[gwB]; endB = rowptr[gwB + 1]; diB = dinv[gwB]; }

    // self-loop rows: issue early
    ushort8 gsA = *(const ushort8*)(G + (size_t)gwA * 128 + q * 8);
    ushort8 gsB = gsA;
    if (okB) gsB = *(const ushort8*)(G + (size_t)gwB * 128 + q * 8);

    float accA[8], accB[8];
#pragma unroll
    for (int j = 0; j < 8; ++j) { accA[j] = 0.f; accB[j] = 0.f; }

    int nitA = (endA - begA + 7) >> 3;
    int nitB = okB ? ((endB - begB + 7) >> 3) : 0;

    auto issue = [&](int beg, int end, int s, ushort8& h0, ushort8& h1,
                     float& m0, float& m1) {
        int i0 = beg + s * 8 + p;
        int i1 = i0 + 4;
        bool v0 = i0 < end, v1 = i1 < end;
        int c0 = col[v0 ? i0 : 0];
        int c1 = col[v1 ? i1 : 0];
        m0 = v0 ? 1.f : 0.f;
        m1 = v1 ? 1.f : 0.f;
        h0 = *(const ushort8*)(G + (size_t)c0 * 128 + q * 8);
        h1 = *(const ushort8*)(G + (size_t)c1 * 128 + q * 8);
    };

    ushort8 A0h0 = {}, A0h1 = {}, A1h0 = {}, A1h1 = {};
    ushort8 B0h0 = {}, B0h1 = {}, B1h0 = {}, B1h1 = {};
    float A0m0 = 0, A0m1 = 0, A1m0 = 0, A1m1 = 0;
    float B0m0 = 0, B0m1 = 0, B1m0 = 0, B1m1 = 0;

    if (nitA > 0) issue(begA, endA, 0, A0h0, A0h1, A0m0, A0m1);
    if (nitB > 0) issue(begB, endB, 0, B0h0, B0h1, B0m0, B0m1);
    if (nitA > 1) issue(begA, endA, 1, A1h0, A1h1, A1m0, A1m1);
    if (nitB > 1) issue(begB, endB, 1, B1h0, B1h1, B1m0, B1m1);

    int nit = nitA > nitB ? nitA : nitB;
    for (int s = 0; s < nit; ++s) {
        if (s < nitA) {
#pragma unroll
            for (int j = 0; j < 8; ++j) {
                accA[j] = fmaf(A0m0, bf2f(A0h0[j]), accA[j]);
                accA[j] = fmaf(A0m1, bf2f(A0h1[j]), accA[j]);
            }
            A0h0 = A1h0; A0h1 = A1h1; A0m0 = A1m0; A0m1 = A1m1;
            if (s + 2 < nitA) issue(begA, endA, s + 2, A1h0, A1h1, A1m0, A1m1);
        }
        if (s < nitB) {
#pragma unroll
            for (int j = 0; j < 8; ++j) {
                accB[j] = fmaf(B0m0, bf2f(B0h0[j]), accB[j]);
                accB[j] = fmaf(B0m1, bf2f(B0h1[j]), accB[j]);
            }
            B0h0 = B1h0; B0h1 = B1h1; B0m0 = B1m0; B0m1 = B1m1;
            if (s + 2 < nitB) issue(begB, endB, s + 2, B1h0, B1h1, B1m0, B1m1);
        }
    }

    // combine 4 edge slots (lanes differing in bits 4,5); A and B interleave
#pragma unroll
    for (int j = 0; j < 8; ++j) {
        accA[j] += __shfl_xor(accA[j], 16);
        accB[j] += __shfl_xor(accB[j], 16);
        accA[j] += __shfl_xor(accA[j], 32);
        accB[j] += __shfl_xor(accB[j], 32);
    }

    if (p == 0) {
        float4 b0 = *(const float4*)(b + q * 8);
        float4 b1 = *(const float4*)(b + q * 8 + 4);
        float oA[8], oB[8];
#pragma unroll
        for (int j = 0; j < 8; ++j) {
            oA[j] = diA * (accA[j] + bf2f(gsA[j]));
            oB[j] = diB * (accB[j] + bf2f(gsB[j]));
        }
        oA[0] += b0.x; oA[1] += b0.y; oA[2] += b0.z; oA[3] += b0.w;
        oA[4] += b1.x; oA[5] += b1.y; oA[6] += b1.z; oA[7] += b1.w;
        oB[0] += b0.x; oB[1] += b0.y; oB[2] += b0.z; oB[3] += b0.w;
        oB[4] += b1.x; oB[5] += b1.y; oB[6] += b1.z; oB[7] += b1.w;
#pragma unroll
        for (int j = 0; j < 8; ++j) {
            oA[j] = fmaxf(oA[j], 0.f);
            oB[j] = fmaxf(oB[j], 0.f);
        }
        if (OUT_BF16) {
            ushort8 ovA, ovB;
#pragma unroll
            for (int j = 0; j < 8; ++j) { ovA[j] = f2bf(oA[j]); ovB[j] = f2bf(oB[j]); }
            *(ushort8*)((unsigned short*)outv + (size_t)gwA * 128 + q * 8) = ovA;
            if (okB)
                *(ushort8*)((unsigned short*)outv + (size_t)gwB * 128 + q * 8) = ovB;
        } else {
            float* out = (float*)outv;
            *(float4*)(out + (size_t)gwA * 128 + q * 8)     = make_float4(oA[0], oA[1], oA[2], oA[3]);
            *(float4*)(out + (size_t)gwA * 128 + q * 8 + 4) = make_float4(oA[4], oA[5], oA[6], oA[7]);
            if (okB) {
                *(float4*)(out + (size_t)gwB * 128 + q * 8)     = make_float4(oB[0], oB[1], oB[2], oB[3]);
                *(float4*)(out + (size_t)gwB * 128 + q * 8 + 4) = make_float4(oB[4], oB[5], oB[6], oB[7]);
            }
        }
    }
}

extern "C" void kernel_launch(void* const* d_in, const int* in_sizes, int n_in,
                              void* d_out, int out_size, void* d_ws, size_t ws_size,
                              hipStream_t stream) {
    const float* x  = (const float*)d_in[0];
    const int*   ei = (const int*)d_in[1];
    const float* W0 = (const float*)d_in[2];
    const float* b0 = (const float*)d_in[3];
    const float* W1 = (const float*)d_in[4];
    const float* b1 = (const float*)d_in[5];
    const float* W2 = (const float*)d_in[6];
    const float* b2 = (const float*)d_in[7];
    float* out = (float*)d_out;

    int N = in_sizes[0] / 128;
    int E = in_sizes[1] / 2;
    int nb = (N + 255) / 256;

    char* wsb = (char*)d_ws;
    size_t off = 0;
    auto alloc = [&](size_t bytes) -> void* {
        void* p = wsb + off;
        off = (off + bytes + 255) & ~(size_t)255;
        return p;
    };
    int*   cnt    = (int*)  alloc((size_t)N * 4);
    int*   rowptr = (int*)  alloc((size_t)(N + 1) * 4);
    float* dinv   = (float*)alloc((size_t)N * 4);
    int*   bsum   = (int*)  alloc((size_t)nb * 4);
    int*   bpre   = (int*)  alloc((size_t)nb * 4);
    int*   rank   = (int*)  alloc((size_t)E * 4);
    int*   col    = (int*)  alloc((size_t)E * 4);
    unsigned short* g  = (unsigned short*)alloc((size_t)N * 128 * 2);
    unsigned short* xB = (unsigned short*)alloc((size_t)N * 128 * 2);
    short* wf0    = (short*)alloc(128 * 128 * 2);
    short* wf1    = (short*)alloc(128 * 128 * 2);
    short* wf2    = (short*)alloc(128 * 128 * 2);

    int n4 = (N + 3) / 4;
    zero_kernel<<<(n4 + 255) / 256, 256, 0, stream>>>((int4*)cnt, n4);
    int e4 = (E + 3) / 4;
    count_rank_kernel<<<(e4 + 255) / 256, 256, 0, stream>>>(ei, cnt, rank, E);
    block_sum_kernel<<<nb, 256, 0, stream>>>(cnt, bsum, N);
    scan_partials_kernel<<<1, 256, 0, stream>>>(bsum, bpre, rowptr, nb, N);
    scan_write_kernel<<<nb, 256, 0, stream>>>(cnt, bpre, rowptr, dinv, N);
    fill_kernel<<<(e4 + 255) / 256, 256, 0, stream>>>(ei, rowptr, rank, col, E);
    wprep_kernel<<<24, 256, 0, stream>>>(W0, W1, W2, wf0, wf1, wf2);

    int gblk = (N + 63) / 64;
    int ablk = (N + 7) / 8;   // 8 nodes per 256-thread block (2 per wave)

    gemm_mfma_kernel<false><<<gblk, 256, 0, stream>>>(x,  wf0, dinv, g, N);
    agg_kernel<true><<<ablk, 256, 0, stream>>>(g, rowptr, col, dinv, b0, xB, N);

    gemm_mfma_kernel<true><<<gblk, 256, 0, stream>>>(xB, wf1, dinv, g, N);
    agg_kernel<true><<<ablk, 256, 0, stream>>>(g, rowptr, col, dinv, b1, xB, N);

    gemm_mfma_kernel<true><<<gblk, 256, 0, stream>>>(xB, wf2, dinv, g, N);
    agg_kernel<false><<<ablk, 256, 0, stream>>>(g, rowptr, col, dinv, b2, out, N);
}